// Round 3
// baseline (650.640 us; speedup 1.0000x reference)
//
#include <hip/hip_runtime.h>
#include <hip/hip_bf16.h>

// RNN: h_t = tanh(x_t U + h_{t-1} W + b), return h_T.  B=256 T=512 D=K=256.
// Phase 0: transpose U -> Ut fp16 [256][264].
// Phase 1: xU = x@U fp16, xu row index = t*256+b. Blocks are t-major (128
//          consecutive t at fixed b) so each block streams a contiguous 128KB
//          window of x instead of 128B chunks at 512KB stride.
// Phase 2: 16 blocks x 16 batch rows x 4 waves (64 cols/wave). W stationary in
//          VGPRs (32 B-frags/wave); h ping-pongs through XOR-swizzled LDS
//          (row stride 512B, granule^(row&7) -> conflict-free b128 reads);
//          xu prefetched 2 steps ahead.

typedef _Float16 half8_t __attribute__((ext_vector_type(8)));
typedef _Float16 half2_t __attribute__((ext_vector_type(2)));
typedef float    float4_t __attribute__((ext_vector_type(4)));

#define MFMA16(a, b, c) __builtin_amdgcn_mfma_f32_16x16x32_f16((a), (b), (c), 0, 0, 0)

__device__ __forceinline__ half2_t pk_h2(float a, float b) {
    auto r = __builtin_amdgcn_cvt_pkrtz(a, b);
    return __builtin_bit_cast(half2_t, r);
}

__device__ __forceinline__ float fast_tanh(float x) {
    float e = __expf(2.0f * x);
    return 1.0f - 2.0f * __builtin_amdgcn_rcpf(e + 1.0f);
}

// ---------------- Phase 0 ----------------
__global__ void transpose_u(const float* __restrict__ U, _Float16* __restrict__ Ut) {
    int id = blockIdx.x * 256 + threadIdx.x;
    int d = id >> 8, n = id & 255;
    Ut[n * 264 + d] = (_Float16)U[id];
}

// ---------------- Phase 1: xU GEMM, t-major 128x256 tile, BK=32, dbuf LDS ---------
__global__ __launch_bounds__(256, 2) void xu_gemm(
    const float* __restrict__ x,        // [256][512][256] fp32
    const _Float16* __restrict__ Ut,    // [256][264] fp16
    half2_t* __restrict__ xu)           // [(t*256+b)][128] half2
{
    __shared__ char lds[61440];
    const int tid = threadIdx.x;
    const int lane = tid & 63, w = tid >> 6, l15 = lane & 15, q = lane >> 4;
    const int bx = blockIdx.x;
    const int b_idx = bx >> 2;          // batch row, fixed per block
    const int t0 = (bx & 3) * 128;      // t-tile start

    float4 ar[4];
    uint4  br[4];

    auto loadA = [&](int it) {
#pragma unroll
        for (int i = 0; i < 4; ++i) {
            int u = tid + 256 * i, row = u >> 3, seg = u & 7;
            ar[i] = *(const float4*)(x + ((size_t)b_idx * 512 + t0 + row) * 256
                                       + it * 32 + seg * 4);
        }
    };
    auto loadB = [&](int it) {
#pragma unroll
        for (int i = 0; i < 4; ++i) {
            int u = tid + 256 * i, p = u >> 2, seg = u & 3;
            int c = 32 * (p >> 5) + 2 * (p & 15) + ((p >> 4) & 1);
            br[i] = *(const uint4*)((const char*)Ut + c * 528 + it * 64 + seg * 16);
        }
    };
    auto writeAB = [&](int s) {
        char* As = lds + s * 10240;
        char* Bs = lds + 20480 + s * 20480;
#pragma unroll
        for (int i = 0; i < 4; ++i) {
            int u = tid + 256 * i, row = u >> 3, seg = u & 7;
            half2_t p0 = pk_h2(ar[i].x, ar[i].y);
            half2_t p1 = pk_h2(ar[i].z, ar[i].w);
            uint2 v;
            v.x = __builtin_bit_cast(unsigned, p0);
            v.y = __builtin_bit_cast(unsigned, p1);
            *(uint2*)(As + row * 80 + seg * 8) = v;
        }
#pragma unroll
        for (int i = 0; i < 4; ++i) {
            int u = tid + 256 * i, p = u >> 2, seg = u & 3;
            *(uint4*)(Bs + p * 80 + seg * 16) = br[i];
        }
    };

    float4_t acc[32];
#pragma unroll
    for (int i = 0; i < 32; ++i) { acc[i][0] = 0.f; acc[i][1] = 0.f; acc[i][2] = 0.f; acc[i][3] = 0.f; }

    loadA(0); loadB(0); writeAB(0);
    __syncthreads();

    for (int it = 0; it < 8; ++it) {
        if (it < 7) { loadA(it + 1); loadB(it + 1); }
        const char* As = lds + (it & 1) * 10240;
        const char* Bs = lds + 20480 + (it & 1) * 20480;
        half8_t af[2];
#pragma unroll
        for (int ms = 0; ms < 2; ++ms)
            af[ms] = *(const half8_t*)(As + (32 * w + 16 * ms + l15) * 80 + q * 16);
#pragma unroll
        for (int ns = 0; ns < 16; ++ns) {
            half8_t bf = *(const half8_t*)(Bs + (16 * ns + l15) * 80 + q * 16);
            acc[ns * 2 + 0] = MFMA16(af[0], bf, acc[ns * 2 + 0]);
            acc[ns * 2 + 1] = MFMA16(af[1], bf, acc[ns * 2 + 1]);
        }
        if (it < 7) writeAB((it + 1) & 1);
        __syncthreads();
    }

#pragma unroll
    for (int ms = 0; ms < 2; ++ms)
#pragma unroll
        for (int j = 0; j < 8; ++j)
#pragma unroll
            for (int i = 0; i < 4; ++i) {
                float v0 = acc[(2 * j) * 2 + ms][i];
                float v1 = acc[(2 * j + 1) * 2 + ms][i];
                half2_t p = pk_h2(v0, v1);
                int t_g = t0 + 32 * w + 16 * ms + q * 4 + i;   // t index (tile row)
                int c = 32 * j + 2 * l15;
                xu[((size_t)t_g * 256 + b_idx) * 128 + (c >> 1)] = p;
            }
}

// ---------------- Phase 2: 512-step scan, 4 waves, swizzled LDS -------------------
// Wave w owns cols [64w,64w+64) as 2 interleaved pairs: pair s covers cols
// [64w+32s, +32), tile tt handles cols 64w+32s+2*l15+tt.
__global__ __launch_bounds__(256, 1) void rnn_scan(
    const half2_t* __restrict__ xu,     // [(t*256+b)][128] half2
    const float* __restrict__ W,        // [256][256] fp32
    const float* __restrict__ bias,     // [256]
    float* __restrict__ out)            // [256][256] fp32
{
    __shared__ char lds[16384];         // h dbuf: 2 x (16 rows x 512B), XOR-swizzled
    const int tid = threadIdx.x;
    const int lane = tid & 63, w = tid >> 6, l15 = lane & 15, q = lane >> 4;
    const int blk = blockIdx.x;

    // W -> B-frags: wf[s][tt][c], k = 32c+8q+j, col = 64w+32s+2*l15+tt
    half8_t wf[2][2][8];
#pragma unroll
    for (int s = 0; s < 2; ++s)
#pragma unroll
        for (int tt = 0; tt < 2; ++tt)
#pragma unroll
            for (int c = 0; c < 8; ++c) {
                half8_t f;
#pragma unroll
                for (int j = 0; j < 8; ++j) {
                    int k = 32 * c + q * 8 + j;
                    f[j] = (_Float16)W[k * 256 + 64 * w + 32 * s + 2 * l15 + tt];
                }
                wf[s][tt][c] = f;
            }
    float bs[2][2];
#pragma unroll
    for (int s = 0; s < 2; ++s)
#pragma unroll
        for (int tt = 0; tt < 2; ++tt)
            bs[s][tt] = bias[64 * w + 32 * s + 2 * l15 + tt];

    // h0 = 0
    for (int i = tid; i < 4096; i += 256) ((int*)lds)[i] = 0;

    // step-invariant swizzled LDS addresses (buffer-0 base)
    int raddr[8];
#pragma unroll
    for (int c = 0; c < 8; ++c)
        raddr[c] = l15 * 512 + 16 * ((4 * c + q) ^ (l15 & 7));
    int waddr[2][4];
#pragma unroll
    for (int s = 0; s < 2; ++s)
#pragma unroll
        for (int i = 0; i < 4; ++i) {
            int r = 4 * q + i;
            int g = 8 * w + 4 * s + (l15 >> 2);
            waddr[s][i] = r * 512 + (g ^ (r & 7)) * 16 + (l15 & 3) * 4;
        }

    const int rowg0 = 16 * blk + 4 * q;
    const int cpair0 = 32 * w + l15;    // + 16*s

    auto load_xu = [&](half2_t (&dst)[8], int t) {
#pragma unroll
        for (int s = 0; s < 2; ++s)
#pragma unroll
            for (int i = 0; i < 4; ++i)
                dst[s * 4 + i] = xu[((size_t)t * 256 + rowg0 + i) * 128 + cpair0 + 16 * s];
    };

    half2_t xc[8], xn[8];
    load_xu(xc, 0);
    load_xu(xn, 1);
    __syncthreads();

    auto step = [&](half2_t (&xreg)[8], int t) {
        float4_t acc[2][2];
#pragma unroll
        for (int s = 0; s < 2; ++s)
#pragma unroll
            for (int tt = 0; tt < 2; ++tt)
#pragma unroll
                for (int i = 0; i < 4; ++i)
                    acc[s][tt][i] = (float)xreg[s * 4 + i][tt];

        int tp = t + 2 > 511 ? 511 : t + 2;     // depth-2 prefetch
        load_xu(xreg, tp);

        const char* base = lds + (t & 1) * 8192;
        half8_t af[8];
#pragma unroll
        for (int c = 0; c < 8; ++c)
            af[c] = *(const half8_t*)(base + raddr[c]);

#pragma unroll
        for (int c = 0; c < 8; ++c)
#pragma unroll
            for (int s = 0; s < 2; ++s)
#pragma unroll
                for (int tt = 0; tt < 2; ++tt)
                    acc[s][tt] = MFMA16(af[c], wf[s][tt][c], acc[s][tt]);

        if (t == 511) {
#pragma unroll
            for (int s = 0; s < 2; ++s)
#pragma unroll
                for (int i = 0; i < 4; ++i) {
                    float v0 = fast_tanh(acc[s][0][i] + bs[s][0]);
                    float v1 = fast_tanh(acc[s][1][i] + bs[s][1]);
                    float2 st; st.x = v0; st.y = v1;
                    *(float2*)(&out[(rowg0 + i) * 256 + 64 * w + 32 * s + 2 * l15]) = st;
                }
        } else {
            char* nb = lds + ((t + 1) & 1) * 8192;
#pragma unroll
            for (int s = 0; s < 2; ++s)
#pragma unroll
                for (int i = 0; i < 4; ++i) {
                    float v0 = fast_tanh(acc[s][0][i] + bs[s][0]);
                    float v1 = fast_tanh(acc[s][1][i] + bs[s][1]);
                    *(half2_t*)(nb + waddr[s][i]) = pk_h2(v0, v1);
                }
        }
        __syncthreads();
    };

    for (int t2 = 0; t2 < 512; t2 += 2) {
        step(xc, t2);
        step(xn, t2 + 1);
    }
}

extern "C" void kernel_launch(void* const* d_in, const int* in_sizes, int n_in,
                              void* d_out, int out_size, void* d_ws, size_t ws_size,
                              hipStream_t stream) {
    const float* x = (const float*)d_in[0];   // [256,512,256]
    const float* U = (const float*)d_in[1];   // [256,256]
    const float* W = (const float*)d_in[2];   // [256,256]
    const float* b = (const float*)d_in[3];   // [256]
    float* out = (float*)d_out;

    char* ws = (char*)d_ws;
    _Float16* Ut = (_Float16*)ws;                       // 135168 B
    half2_t*  xu = (half2_t*)(ws + 262144);             // 67,108,864 B

    transpose_u<<<256, 256, 0, stream>>>(U, Ut);
    xu_gemm<<<1024, 256, 0, stream>>>(x, Ut, xu);
    rnn_scan<<<16, 256, 0, stream>>>(xu, W, b, out);
}